// Round 7
// baseline (116.834 us; speedup 1.0000x reference)
//
#include <hip/hip_runtime.h>
#include <hip/hip_bf16.h>
#include <stdint.h>

#define NB    4096
#define NROWS 8192
#define DIM   512
#define BM    128
#define BK    64
#define NKS   (DIM / BK)              // 8 K-steps
#define NTILES 2080                   // upper triangle of 64x64 tile grid

typedef __attribute__((ext_vector_type(8))) short          bf16x8;
typedef __attribute__((ext_vector_type(4))) float          f32x4;
typedef __attribute__((ext_vector_type(8))) unsigned short u16x8;

__device__ __forceinline__ unsigned short f2bf(float f) {
  uint32_t u = __float_as_uint(f);
  u += 0x7fffu + ((u >> 16) & 1u);   // round-to-nearest-even
  return (unsigned short)(u >> 16);
}
__device__ __forceinline__ float bf2f(unsigned short h) {
  return __uint_as_float(((uint32_t)h) << 16);
}
__device__ __forceinline__ void gload_lds16(const void* g, void* l) {
  __builtin_amdgcn_global_load_lds(
      (const __attribute__((address_space(1))) void*)g,
      (__attribute__((address_space(3))) void*)l, 16, 0, 0);
}

// ---- Kernel 1: normalize rows -> bf16 P, fused pos partials, zero rowsum --
__global__ __launch_bounds__(256) void normalize_pos_kernel(
    const float* __restrict__ zi, const float* __restrict__ zj,
    unsigned short* __restrict__ p, float* __restrict__ rowsum,
    float* __restrict__ posp, int* __restrict__ ctr) {
  __shared__ float ws4[4];
  const int wave = threadIdx.x >> 6;
  const int lane = threadIdx.x & 63;
  const int i    = blockIdx.x * 4 + wave;

  int gt = blockIdx.x * 256 + threadIdx.x;
  if (gt < NROWS) rowsum[gt] = 0.f;
  if (blockIdx.x == 0 && threadIdx.x < 8) ctr[threadIdx.x] = 0;

  const float4* sa = (const float4*)(zi + (size_t)i * DIM);
  const float4* sb = (const float4*)(zj + (size_t)i * DIM);
  float4 a0 = sa[lane * 2], a1 = sa[lane * 2 + 1];
  float4 b0 = sb[lane * 2], b1 = sb[lane * 2 + 1];
  float va[8] = {a0.x, a0.y, a0.z, a0.w, a1.x, a1.y, a1.z, a1.w};
  float vb[8] = {b0.x, b0.y, b0.z, b0.w, b1.x, b1.y, b1.z, b1.w};
  float ssa = 0.f, ssb = 0.f;
#pragma unroll
  for (int j = 0; j < 8; ++j) { ssa += va[j] * va[j]; ssb += vb[j] * vb[j]; }
#pragma unroll
  for (int off = 32; off; off >>= 1) {
    ssa += __shfl_xor(ssa, off);
    ssb += __shfl_xor(ssb, off);
  }
  float inva = rsqrtf(ssa), invb = rsqrtf(ssb);
  u16x8 ha, hb;
#pragma unroll
  for (int j = 0; j < 8; ++j) { ha[j] = f2bf(va[j] * inva); hb[j] = f2bf(vb[j] * invb); }
  *(u16x8*)(p + (size_t)i * DIM + lane * 8)        = ha;
  *(u16x8*)(p + (size_t)(i + NB) * DIM + lane * 8) = hb;

  float d = 0.f;
#pragma unroll
  for (int j = 0; j < 8; ++j) d += bf2f(ha[j]) * bf2f(hb[j]);
#pragma unroll
  for (int off = 32; off; off >>= 1) d += __shfl_xor(d, off);
  if (lane == 0) ws4[wave] = d;
  __syncthreads();
  if (threadIdx.x == 0)
    posp[blockIdx.x] = 4.0f * (ws4[0] + ws4[1] + ws4[2] + ws4[3]);
}

// decode (xcd x, local slot l) -> tile (bi,bj); supertile partition:
//   x<6 : full 16x16 square of tiles, quota 256
//   x=6 : diag halves of supers (0,0)+(1,1); x=7 : (2,2)+(3,3); quota 272
__device__ __forceinline__ void decode_tile(int x, int l, int* pbi, int* pbj) {
  if (x < 6) {
    const int sqi[6] = {0, 0, 0, 1, 1, 2};
    const int sqj[6] = {1, 2, 3, 2, 3, 3};
    *pbi = sqi[x] * 16 + (l >> 4);
    *pbj = sqj[x] * 16 + (l & 15);
  } else {
    int s  = (x == 6) ? 0 : 2;
    int ll = l;
    if (ll >= 136) { ll -= 136; s += 1; }
    int i = 0;
    while ((i + 1) * (33 - (i + 1)) / 2 <= ll) ++i;
    int j = i + (ll - i * (33 - i) / 2);
    *pbi = s * 16 + i;
    *pbj = s * 16 + j;
  }
}

// ---- Kernel 2: symmetric fused S = 2*P*P^T -> exp -> row+col sums ---------
// Body identical to R6 (BK=64 single-buffer, best measured). Single change:
// tiles are CLAIMED at runtime by the block's REAL XCD (s_getreg XCC_ID)
// from that XCD's supertile queue -> guaranteed panel-in-my-L2 affinity.
__global__ __launch_bounds__(256) void simexp_kernel(
    const unsigned short* __restrict__ p, float* __restrict__ rowsum,
    int* __restrict__ ctr) {
  __shared__ __align__(16) unsigned short As[BM * BK];   // 16 KB
  __shared__ __align__(16) unsigned short Bs[BM * BK];   // 16 KB
  __shared__ int sTile;

  if (threadIdx.x == 0) {
    // hwreg(HW_REG_XCC_ID=20, offset 0, size 32) -> imm 20 | (31<<11)
    uint32_t xcc = __builtin_amdgcn_s_getreg(20 | (31 << 11)) & 7;
    int enc = -1;
    for (int k = 0; k < 8; ++k) {
      int x     = (xcc + k) & 7;
      int quota = (x < 6) ? 256 : 272;
      int s     = atomicAdd(&ctr[x], 1);
      if (s < quota) { enc = (x << 9) | s; break; }
    }
    sTile = enc;   // -1 only possible when all 2080 tiles already claimed
  }
  __syncthreads();
  const int enc = sTile;
  if (enc < 0) return;
  int bi, bj;
  decode_tile(enc >> 9, enc & 511, &bi, &bj);
  const bool diag = (bi == bj);

  const int tid  = threadIdx.x;
  const int wave = tid >> 6;
  const int lane = tid & 63;
  const int wm   = wave >> 1;
  const int wn   = wave & 1;
  const int frow = lane & 15;
  const int kc   = lane >> 4;      // 0..3

  const unsigned short* pa = p + (size_t)(bi * BM) * DIM;
  const unsigned short* pb = p + (size_t)(bj * BM) * DIM;

  const int srow8 = lane >> 3;               // 0..7
  const int gch   = (lane & 7) ^ srow8;      // pre-swizzled 16B chunk

  // ds_read byte offsets: row*128 + ((kk*4+kc)^(row&7))*16, kk in {0,1}
  int offA[4][2], offB[4][2];
#pragma unroll
  for (int m = 0; m < 4; ++m) {
    int row = wm * 64 + m * 16 + frow;
#pragma unroll
    for (int kk = 0; kk < 2; ++kk)
      offA[m][kk] = row * 128 + ((kk * 4 + kc) ^ (row & 7)) * 16;
  }
#pragma unroll
  for (int n = 0; n < 4; ++n) {
    int row = wn * 64 + n * 16 + frow;
#pragma unroll
    for (int kk = 0; kk < 2; ++kk)
      offB[n][kk] = row * 128 + ((kk * 4 + kc) ^ (row & 7)) * 16;
  }

  f32x4 acc[4][4] = {};

  for (int t = 0; t < NKS; ++t) {
    const int k0 = t * BK;
#pragma unroll
    for (int q = 0; q < 4; ++q) {
      int rbase = wave * 32 + q * 8;
      gload_lds16(pa + (size_t)(rbase + srow8) * DIM + k0 + gch * 8,
                  (char*)As + rbase * 128);
      gload_lds16(pb + (size_t)(rbase + srow8) * DIM + k0 + gch * 8,
                  (char*)Bs + rbase * 128);
    }
    __syncthreads();

    bf16x8 af[4][2], bf_[4][2];
#pragma unroll
    for (int m = 0; m < 4; ++m) {
      af[m][0] = *(const bf16x8*)((const char*)As + offA[m][0]);
      af[m][1] = *(const bf16x8*)((const char*)As + offA[m][1]);
    }
#pragma unroll
    for (int n = 0; n < 4; ++n) {
      bf_[n][0] = *(const bf16x8*)((const char*)Bs + offB[n][0]);
      bf_[n][1] = *(const bf16x8*)((const char*)Bs + offB[n][1]);
    }
#pragma unroll
    for (int m = 0; m < 4; ++m)
#pragma unroll
      for (int n = 0; n < 4; ++n) {
        acc[m][n] = __builtin_amdgcn_mfma_f32_16x16x32_bf16(
            af[m][0], bf_[n][0], acc[m][n], 0, 0, 0);
        acc[m][n] = __builtin_amdgcn_mfma_f32_16x16x32_bf16(
            af[m][1], bf_[n][1], acc[m][n], 0, 0, 0);
      }
    __syncthreads();
  }

  // epilogue: e = exp(2s); rowsum[row] += e; rowsum[col] += e if off-diag
  const int r4 = lane >> 4;   // C/D: col = lane&15, row = (lane>>4)*4 + reg
  const int cl = lane & 15;

  float rowpart[4][4];
  float colpart[4] = {0.f, 0.f, 0.f, 0.f};

  if (diag) {
#pragma unroll
    for (int m = 0; m < 4; ++m)
#pragma unroll
      for (int r = 0; r < 4; ++r) {
        int grow = bi * BM + wm * 64 + m * 16 + r4 * 4 + r;
        float s = 0.f;
#pragma unroll
        for (int n = 0; n < 4; ++n) {
          int gcol = bj * BM + wn * 64 + n * 16 + cl;
          float e  = __expf(2.0f * acc[m][n][r]);
          s += (grow == gcol) ? 0.f : e;
        }
        rowpart[m][r] = s;
      }
  } else {
#pragma unroll
    for (int m = 0; m < 4; ++m)
#pragma unroll
      for (int r = 0; r < 4; ++r) {
        float s = 0.f;
#pragma unroll
        for (int n = 0; n < 4; ++n) {
          float e = __expf(2.0f * acc[m][n][r]);
          s += e;
          colpart[n] += e;
        }
        rowpart[m][r] = s;
      }
  }

#pragma unroll
  for (int m = 0; m < 4; ++m)
#pragma unroll
    for (int r = 0; r < 4; ++r) {
      float s = rowpart[m][r];
      s += __shfl_xor(s, 1);
      s += __shfl_xor(s, 2);
      s += __shfl_xor(s, 4);
      s += __shfl_xor(s, 8);
      if (cl == 0) {
        int grow = bi * BM + wm * 64 + m * 16 + r4 * 4 + r;
        atomicAdd(&rowsum[grow], s);
      }
    }

  if (!diag) {
#pragma unroll
    for (int n = 0; n < 4; ++n) {
      float c = colpart[n];
      c += __shfl_xor(c, 16);
      c += __shfl_xor(c, 32);
      if (r4 == 0) {
        int gcol = bj * BM + wn * 64 + n * 16 + cl;
        atomicAdd(&rowsum[gcol], c);
      }
    }
  }
}

// ---- Kernel 3: finalize loss ---------------------------------------------
__global__ __launch_bounds__(256) void finalize_kernel(
    const float* __restrict__ rowsum, const float* __restrict__ posp,
    float* __restrict__ out) {
  __shared__ float ws4[4];
  int tid = threadIdx.x;
  float v = 0.f;
  for (int i = tid; i < NROWS; i += 256) v += logf(rowsum[i]);
  for (int i = tid; i < 1024; i += 256) v -= posp[i];
#pragma unroll
  for (int off = 32; off; off >>= 1) v += __shfl_xor(v, off);
  if ((tid & 63) == 0) ws4[tid >> 6] = v;
  __syncthreads();
  if (tid == 0)
    out[0] = (ws4[0] + ws4[1] + ws4[2] + ws4[3]) / (float)NROWS;
}

extern "C" void kernel_launch(void* const* d_in, const int* in_sizes, int n_in,
                              void* d_out, int out_size, void* d_ws,
                              size_t ws_size, hipStream_t stream) {
  const float* zi = (const float*)d_in[0];
  const float* zj = (const float*)d_in[1];
  float* out      = (float*)d_out;

  char* ws          = (char*)d_ws;
  unsigned short* p = (unsigned short*)ws;                        // 8 MB bf16
  float* rowsum     = (float*)(ws + (size_t)NROWS * DIM * 2);     // 32 KB
  float* posp       = rowsum + NROWS;                             // 4 KB
  int*   ctr        = (int*)(posp + 1024);                        // 32 B

  normalize_pos_kernel<<<NB / 4, 256, 0, stream>>>(zi, zj, p, rowsum, posp, ctr);
  simexp_kernel<<<NTILES, 256, 0, stream>>>(p, rowsum, ctr);
  finalize_kernel<<<1, 256, 0, stream>>>(rowsum, posp, out);
}

// Round 8
// 90.165 us; speedup vs baseline: 1.2958x; 1.2958x over previous
//
#include <hip/hip_runtime.h>
#include <hip/hip_bf16.h>
#include <stdint.h>

#define NB    4096
#define NROWS 8192
#define DIM   512
#define BM    128
#define BKB   128                     // K-bytes (fp8) per LDS tile = K elems
#define NKT   (DIM / BKB)             // 4 K-tiles
#define NBLK  2176                    // 8 XCDs x 272 (96 early-exit)

typedef __attribute__((ext_vector_type(4))) float f32x4;
typedef __attribute__((ext_vector_type(4))) int   i32x4;
typedef __attribute__((ext_vector_type(8))) int   i32x8;

#define SCALE_E8M0 0x7B7B7B7Bu   // 2^-4 per 32-elem block, all blocks

// f32 -> OCP e4m3fn, RNE. Inputs |x| <= ~8 here (no sat needed).
__device__ __forceinline__ unsigned char f2e4m3(float x) {
  uint32_t u = __float_as_uint(x);
  uint32_t s = (u >> 24) & 0x80u;
  uint32_t e = (u >> 23) & 0xffu;
  if (e < 117u) return (unsigned char)s;          // < 2^-10 -> 0
  if (e >= 121u) {                                // normal fp8 range
    u += 0x7FFFFu + ((u >> 20) & 1u);             // RNE on mantissa bit 20
    e = (u >> 23) & 0xffu;
    uint32_t m = (u >> 20) & 7u;
    return (unsigned char)(s | ((e - 120u) << 3) | m);
  }
  float af = __uint_as_float(u & 0x7fffffffu);    // subnormal: step 2^-9
  int q = (int)(af * 512.0f + 0.5f);
  return (unsigned char)(q > 7 ? (s | 0x08u) : (s | (uint32_t)q));
}

__device__ __forceinline__ void gload_lds16(const void* g, void* l) {
  __builtin_amdgcn_global_load_lds(
      (const __attribute__((address_space(1))) void*)g,
      (__attribute__((address_space(3))) void*)l, 16, 0, 0);
}

__device__ __forceinline__ i32x8 ld_frag(const char* base, int o0, int o1) {
  i32x4 lo = *(const i32x4*)(base + o0);
  i32x4 hi = *(const i32x4*)(base + o1);
  i32x8 r = {lo[0], lo[1], lo[2], lo[3], hi[0], hi[1], hi[2], hi[3]};
  return r;
}

// ---- Kernel 1: normalize rows -> fp8 P (v*16, e4m3), pos partials, zero ---
__global__ __launch_bounds__(256) void normalize_pos_kernel(
    const float* __restrict__ zi, const float* __restrict__ zj,
    unsigned char* __restrict__ p, float* __restrict__ rowsum,
    float* __restrict__ posp) {
  __shared__ float ws4[4];
  const int wave = threadIdx.x >> 6;
  const int lane = threadIdx.x & 63;
  const int i    = blockIdx.x * 4 + wave;          // 0..4095

  int gt = blockIdx.x * 256 + threadIdx.x;
  if (gt < NROWS) rowsum[gt] = 0.f;

  const float4* sa = (const float4*)(zi + (size_t)i * DIM);
  const float4* sb = (const float4*)(zj + (size_t)i * DIM);
  float4 a0 = sa[lane * 2], a1 = sa[lane * 2 + 1];
  float4 b0 = sb[lane * 2], b1 = sb[lane * 2 + 1];
  float va[8] = {a0.x, a0.y, a0.z, a0.w, a1.x, a1.y, a1.z, a1.w};
  float vb[8] = {b0.x, b0.y, b0.z, b0.w, b1.x, b1.y, b1.z, b1.w};
  float ssa = 0.f, ssb = 0.f;
#pragma unroll
  for (int j = 0; j < 8; ++j) { ssa += va[j] * va[j]; ssb += vb[j] * vb[j]; }
#pragma unroll
  for (int off = 32; off; off >>= 1) {
    ssa += __shfl_xor(ssa, off);
    ssb += __shfl_xor(ssb, off);
  }
  float inva = rsqrtf(ssa), invb = rsqrtf(ssb);

  union { unsigned char b[8]; uint2 v; } qa, qb;
  float d = 0.f;
#pragma unroll
  for (int j = 0; j < 8; ++j) {
    float na = va[j] * inva, nb = vb[j] * invb;
    qa.b[j] = f2e4m3(na * 16.0f);
    qb.b[j] = f2e4m3(nb * 16.0f);
    d += na * nb;
  }
  *(uint2*)(p + (size_t)i * DIM + lane * 8)        = qa.v;
  *(uint2*)(p + (size_t)(i + NB) * DIM + lane * 8) = qb.v;

#pragma unroll
  for (int off = 32; off; off >>= 1) d += __shfl_xor(d, off);
  if (lane == 0) ws4[wave] = d;
  __syncthreads();
  if (threadIdx.x == 0)
    posp[blockIdx.x] = 4.0f * (ws4[0] + ws4[1] + ws4[2] + ws4[3]);
}

// ---- Kernel 2: symmetric fused S = 2*P*P^T (MX-fp8) -> exp -> row+col sums
// R6 structure (static supertile map, single-buffer syncthreads loop) with
// mfma_scale_f32_16x16x128_f8f6f4: 4 K-tiles of 128, 16 MFMA/wave/tile.
// LDS rows 128B, 8 chunks of 16B, chunk ^= (row&7) swizzle via pre-swizzled
// global source (linear LDS dest) — measured conflict-free family.
__global__ __launch_bounds__(256) void simexp_kernel(
    const unsigned char* __restrict__ p, float* __restrict__ rowsum) {
  __shared__ __align__(16) unsigned char As[BM * BKB];   // 16 KB
  __shared__ __align__(16) unsigned char Bs[BM * BKB];   // 16 KB

  const int x = blockIdx.x & 7;          // XCD (round-robin heuristic)
  const int l = blockIdx.x >> 3;         // 0..271 local index
  int bi, bj;
  if (x < 6) {
    if (l >= 256) return;                // uniform early-exit, before barriers
    const int sqi[6] = {0, 0, 0, 1, 1, 2};
    const int sqj[6] = {1, 2, 3, 2, 3, 3};
    bi = sqi[x] * 16 + (l >> 4);
    bj = sqj[x] * 16 + (l & 15);
  } else {
    int s  = (x == 6) ? 0 : 2;
    int ll = l;
    if (ll >= 136) { ll -= 136; s += 1; }
    int i = 0;
    while ((i + 1) * (33 - (i + 1)) / 2 <= ll) ++i;
    int j = i + (ll - i * (33 - i) / 2);
    bi = s * 16 + i;
    bj = s * 16 + j;
  }
  const bool diag = (bi == bj);

  const int tid  = threadIdx.x;
  const int wave = tid >> 6;
  const int lane = tid & 63;
  const int wm   = wave >> 1;
  const int wn   = wave & 1;
  const int frow = lane & 15;
  const int kc   = lane >> 4;      // 0..3 : 32-elem k-block

  const unsigned char* pa = p + (size_t)(bi * BM) * DIM;
  const unsigned char* pb = p + (size_t)(bj * BM) * DIM;

  const int srow8 = lane >> 3;               // 0..7
  const int gch   = (lane & 7) ^ srow8;      // pre-swizzled 16B chunk

  // ds_read byte offsets: row*128 + ((kc*2+j) ^ (row&7))*16, j in {0,1}
  int offA[4][2], offB[4][2];
#pragma unroll
  for (int m = 0; m < 4; ++m) {
    int row = wm * 64 + m * 16 + frow;
#pragma unroll
    for (int j = 0; j < 2; ++j)
      offA[m][j] = row * 128 + ((kc * 2 + j) ^ (row & 7)) * 16;
  }
#pragma unroll
  for (int n = 0; n < 4; ++n) {
    int row = wn * 64 + n * 16 + frow;
#pragma unroll
    for (int j = 0; j < 2; ++j)
      offB[n][j] = row * 128 + ((kc * 2 + j) ^ (row & 7)) * 16;
  }

  f32x4 acc[4][4] = {};

  for (int t = 0; t < NKT; ++t) {
    const int k0 = t * BKB;
#pragma unroll
    for (int q = 0; q < 4; ++q) {
      int rbase = q * 32 + wave * 8;
      gload_lds16(pa + (size_t)(rbase + srow8) * DIM + k0 + gch * 16,
                  (char*)As + rbase * 128);
      gload_lds16(pb + (size_t)(rbase + srow8) * DIM + k0 + gch * 16,
                  (char*)Bs + rbase * 128);
    }
    __syncthreads();

    i32x8 af[4], bfr[4];
#pragma unroll
    for (int m = 0; m < 4; ++m)
      af[m] = ld_frag((const char*)As, offA[m][0], offA[m][1]);
#pragma unroll
    for (int n = 0; n < 4; ++n)
      bfr[n] = ld_frag((const char*)Bs, offB[n][0], offB[n][1]);

#pragma unroll
    for (int m = 0; m < 4; ++m)
#pragma unroll
      for (int n = 0; n < 4; ++n)
        acc[m][n] = __builtin_amdgcn_mfma_scale_f32_16x16x128_f8f6f4(
            af[m], bfr[n], acc[m][n],
            0 /*cbsz: fp8*/, 0 /*blgp: fp8*/,
            0, SCALE_E8M0, 0, SCALE_E8M0);
    __syncthreads();
  }

  // epilogue: e = exp(2s); rowsum[row] += e; rowsum[col] += e if off-diag
  const int r4 = lane >> 4;   // C/D: col = lane&15, row = (lane>>4)*4 + reg
  const int cl = lane & 15;

  float rowpart[4][4];
  float colpart[4] = {0.f, 0.f, 0.f, 0.f};

  if (diag) {
#pragma unroll
    for (int m = 0; m < 4; ++m)
#pragma unroll
      for (int r = 0; r < 4; ++r) {
        int grow = bi * BM + wm * 64 + m * 16 + r4 * 4 + r;
        float s = 0.f;
#pragma unroll
        for (int n = 0; n < 4; ++n) {
          int gcol = bj * BM + wn * 64 + n * 16 + cl;
          float e  = __expf(2.0f * acc[m][n][r]);
          s += (grow == gcol) ? 0.f : e;
        }
        rowpart[m][r] = s;
      }
  } else {
#pragma unroll
    for (int m = 0; m < 4; ++m)
#pragma unroll
      for (int r = 0; r < 4; ++r) {
        float s = 0.f;
#pragma unroll
        for (int n = 0; n < 4; ++n) {
          float e = __expf(2.0f * acc[m][n][r]);
          s += e;
          colpart[n] += e;
        }
        rowpart[m][r] = s;
      }
  }

#pragma unroll
  for (int m = 0; m < 4; ++m)
#pragma unroll
    for (int r = 0; r < 4; ++r) {
      float s = rowpart[m][r];
      s += __shfl_xor(s, 1);
      s += __shfl_xor(s, 2);
      s += __shfl_xor(s, 4);
      s += __shfl_xor(s, 8);
      if (cl == 0) {
        int grow = bi * BM + wm * 64 + m * 16 + r4 * 4 + r;
        atomicAdd(&rowsum[grow], s);
      }
    }

  if (!diag) {
#pragma unroll
    for (int n = 0; n < 4; ++n) {
      float c = colpart[n];
      c += __shfl_xor(c, 16);
      c += __shfl_xor(c, 32);
      if (r4 == 0) {
        int gcol = bj * BM + wn * 64 + n * 16 + cl;
        atomicAdd(&rowsum[gcol], c);
      }
    }
  }
}

// ---- Kernel 3: finalize loss ---------------------------------------------
__global__ __launch_bounds__(256) void finalize_kernel(
    const float* __restrict__ rowsum, const float* __restrict__ posp,
    float* __restrict__ out) {
  __shared__ float ws4[4];
  int tid = threadIdx.x;
  float v = 0.f;
  for (int i = tid; i < NROWS; i += 256) v += logf(rowsum[i]);
  for (int i = tid; i < 1024; i += 256) v -= posp[i];
#pragma unroll
  for (int off = 32; off; off >>= 1) v += __shfl_xor(v, off);
  if ((tid & 63) == 0) ws4[tid >> 6] = v;
  __syncthreads();
  if (tid == 0)
    out[0] = (ws4[0] + ws4[1] + ws4[2] + ws4[3]) / (float)NROWS;
}

extern "C" void kernel_launch(void* const* d_in, const int* in_sizes, int n_in,
                              void* d_out, int out_size, void* d_ws,
                              size_t ws_size, hipStream_t stream) {
  const float* zi = (const float*)d_in[0];
  const float* zj = (const float*)d_in[1];
  float* out      = (float*)d_out;

  char* ws          = (char*)d_ws;
  unsigned char* p  = (unsigned char*)ws;                        // 4 MB fp8
  float* rowsum     = (float*)(ws + (size_t)NROWS * DIM);        // 32 KB
  float* posp       = rowsum + NROWS;                            // 4 KB

  normalize_pos_kernel<<<NB / 4, 256, 0, stream>>>(zi, zj, p, rowsum, posp);
  simexp_kernel<<<NBLK, 256, 0, stream>>>(p, rowsum);
  finalize_kernel<<<1, 256, 0, stream>>>(rowsum, posp, out);
}